// Round 10
// baseline (249.075 us; speedup 1.0000x reference)
//
#include <hip/hip_runtime.h>
#include <math.h>

#define N_NODES 100000
#define E_EDGES 1600000
#define HDIM 128
#define NEG_SLOPE 0.01f
#define EPS_DEN 1e-16f
#define ROW_CAP 64      // in-degree ~ Poisson(16); P(deg>=64) ~ 1e-20

#define SCAN_BLOCKS 256
#define SCAN_TPB 256
#define SCAN_CHUNK ((N_NODES + SCAN_BLOCKS - 1) / SCAN_BLOCKS)   // 391
#define SCAN_STRIP ((SCAN_CHUNK + SCAN_TPB - 1) / SCAN_TPB)      // 2

__device__ __forceinline__ float lrelu(float e) {
    return e > 0.f ? e : NEG_SLOPE * e;
}

// K1: fused per-node scores + optional bf16 cast of x + zero denom/cursor.
// One wave per node; float2 row loads; bf16 row written as packed u32.
template <bool BF16>
__global__ __launch_bounds__(256) void k_scores_cast(
    const float* __restrict__ x, const float* __restrict__ w_i,
    const float* __restrict__ w_j, float* __restrict__ s_i,
    float* __restrict__ s_j, unsigned* __restrict__ xb2,
    float* __restrict__ denom, int* __restrict__ cursor) {
    int wave = (blockIdx.x * blockDim.x + threadIdx.x) >> 6;
    int lane = threadIdx.x & 63;
    if (wave >= N_NODES) return;
    const float2* row = (const float2*)(x + (size_t)wave * HDIM);
    float2 v  = row[lane];
    float2 wi = ((const float2*)w_i)[lane];
    float2 wj = ((const float2*)w_j)[lane];
    if (BF16) {
        unsigned a = __float_as_uint(v.x);
        unsigned b = __float_as_uint(v.y);
        unsigned lo = (a + 0x7FFFu + ((a >> 16) & 1u)) >> 16;
        unsigned hi = (b + 0x7FFFu + ((b >> 16) & 1u)) >> 16;
        xb2[(size_t)wave * (HDIM / 2) + lane] = lo | (hi << 16);
    }
    float vi = v.x * wi.x + v.y * wi.y;
    float vj = v.x * wj.x + v.y * wj.y;
#pragma unroll
    for (int off = 32; off; off >>= 1) {
        vi += __shfl_down(vi, off);
        vj += __shfl_down(vj, off);
    }
    if (lane == 0) {
        s_i[wave] = vi;
        s_j[wave] = vj;
        denom[wave] = 0.f;
        cursor[wave] = 0;
    }
}

// K2 (pad path): fused scatter, 2 edges per thread (deeper memory queues).
// denom[j] += ex; slot via cursor atomic; store {j, ex} into fixed-cap row.
__global__ __launch_bounds__(256) void k_scatter_pad2(
    const int2* __restrict__ ej2, const int2* __restrict__ ei2,
    const float* __restrict__ s_i, const float* __restrict__ s_j,
    float* __restrict__ denom, int* __restrict__ cursor,
    int2* __restrict__ csr) {
    int t = blockIdx.x * blockDim.x + threadIdx.x;
    if (t >= E_EDGES / 2) return;
    int2 j2 = ej2[t];
    int2 i2 = ei2[t];
    float ex0 = expf(lrelu(s_i[i2.x] + s_j[j2.x]));
    float ex1 = expf(lrelu(s_i[i2.y] + s_j[j2.y]));
    atomicAdd(&denom[j2.x], ex0);
    atomicAdd(&denom[j2.y], ex1);
    int s0 = atomicAdd(&cursor[i2.x], 1);
    int s1 = atomicAdd(&cursor[i2.y], 1);
    if (s0 < ROW_CAP) {
        int2 v; v.x = j2.x; v.y = __float_as_int(ex0);
        csr[(size_t)i2.x * ROW_CAP + s0] = v;
    }
    if (s1 < ROW_CAP) {
        int2 v; v.x = j2.y; v.y = __float_as_int(ex1);
        csr[(size_t)i2.y * ROW_CAP + s1] = v;
    }
}

// K3 (pad path): gather SPMM + ReLU — byte-identical structure to r9
// (validated). Two nodes per wave; independent 32-lane halves; width-32
// shuffles; uniform trip count; alpha = stored_ex/(denom[j]+eps) at stage.
template <bool BF16>
__global__ __launch_bounds__(256) void k_gather_pad(
    const int* __restrict__ cursor, const int2* __restrict__ csr,
    const float* __restrict__ denom, const float* __restrict__ x,
    const unsigned short* __restrict__ xb, float* __restrict__ out) {
    int wave = (blockIdx.x * blockDim.x + threadIdx.x) >> 6;
    int half = (threadIdx.x >> 5) & 1;
    int l32  = threadIdx.x & 31;
    int node = wave * 2 + half;
    if (node >= N_NODES) return;
    int len = cursor[node];
    if (len > ROW_CAP) len = ROW_CAP;
    int start = node * ROW_CAP;
    float ax = 0.f, ay = 0.f, az = 0.f, aw = 0.f;
    for (int off = 0; off < len; off += 32) {
        int m = len - off;
        if (m > 32) m = 32;
        int jv = 0;
        float av = 0.f;
        if (l32 < m) {
            int2 v = csr[start + off + l32];
            jv = v.x;
            av = __int_as_float(v.y) / (denom[jv] + EPS_DEN);
        }
        for (int e = 0; e < m; ++e) {
            int j = __shfl(jv, e, 32);
            float a = __shfl(av, e, 32);
            if (BF16) {
                const uint2* xr = (const uint2*)(xb + (size_t)j * HDIM);
                uint2 v = xr[l32];
                ax += a * __uint_as_float((v.x & 0xFFFFu) << 16);
                ay += a * __uint_as_float(v.x & 0xFFFF0000u);
                az += a * __uint_as_float((v.y & 0xFFFFu) << 16);
                aw += a * __uint_as_float(v.y & 0xFFFF0000u);
            } else {
                const float4* xr = (const float4*)(x + (size_t)j * HDIM);
                float4 v = xr[l32];
                ax += a * v.x;
                ay += a * v.y;
                az += a * v.z;
                aw += a * v.w;
            }
        }
    }
    float4 o;
    o.x = fmaxf(ax, 0.f);
    o.y = fmaxf(ay, 0.f);
    o.z = fmaxf(az, 0.f);
    o.w = fmaxf(aw, 0.f);
    ((float4*)(out + (size_t)node * HDIM))[l32] = o;
}

// ======== dense fallback (r8/r9-verified) ========
__global__ __launch_bounds__(256) void k_count(
    const int4* __restrict__ ei4, int* __restrict__ counts) {
    int t = blockIdx.x * blockDim.x + threadIdx.x;
    if (t >= E_EDGES / 4) return;
    int4 v = ei4[t];
    atomicAdd(&counts[v.x], 1);
    atomicAdd(&counts[v.y], 1);
    atomicAdd(&counts[v.z], 1);
    atomicAdd(&counts[v.w], 1);
}

__global__ __launch_bounds__(SCAN_TPB) void k_scanA(
    const int* __restrict__ data, int n, int* __restrict__ blocksum) {
    __shared__ int red[SCAN_TPB];
    int b = blockIdx.x, t = threadIdx.x;
    int begin = b * SCAN_CHUNK + t * SCAN_STRIP;
    int lim = (b + 1) * SCAN_CHUNK;
    if (lim > n) lim = n;
    int end = begin + SCAN_STRIP;
    if (end > lim) end = lim;
    int s = 0;
    for (int k = begin; k < end; ++k) s += data[k];
    red[t] = s;
    __syncthreads();
    for (int off = SCAN_TPB / 2; off; off >>= 1) {
        if (t < off) red[t] += red[t + off];
        __syncthreads();
    }
    if (t == 0) blocksum[b] = red[0];
}

__global__ __launch_bounds__(SCAN_BLOCKS) void k_scanB(int* __restrict__ blocksum) {
    __shared__ int s[SCAN_BLOCKS];
    int t = threadIdx.x;
    s[t] = blocksum[t];
    __syncthreads();
    for (int off = 1; off < SCAN_BLOCKS; off <<= 1) {
        int v = (t >= off) ? s[t - off] : 0;
        __syncthreads();
        s[t] += v;
        __syncthreads();
    }
    blocksum[t] = (t == 0) ? 0 : s[t - 1];
}

__global__ __launch_bounds__(SCAN_TPB) void k_scanC(
    int* __restrict__ data, int n, const int* __restrict__ blocksum) {
    __shared__ int s[SCAN_TPB];
    int b = blockIdx.x, t = threadIdx.x;
    int begin = b * SCAN_CHUNK + t * SCAN_STRIP;
    int lim = (b + 1) * SCAN_CHUNK;
    if (lim > n) lim = n;
    int v0 = 0, v1 = 0;            // SCAN_STRIP == 2
    if (begin < lim)      v0 = data[begin];
    if (begin + 1 < lim)  v1 = data[begin + 1];
    s[t] = v0 + v1;
    __syncthreads();
    for (int off = 1; off < SCAN_TPB; off <<= 1) {
        int v = (t >= off) ? s[t - off] : 0;
        __syncthreads();
        s[t] += v;
        __syncthreads();
    }
    int pref = blocksum[b] + ((t == 0) ? 0 : s[t - 1]);
    if (begin < lim)     data[begin] = pref;
    if (begin + 1 < lim) data[begin + 1] = pref + v0;
}

__global__ __launch_bounds__(256) void k_scatter_denom(
    const int* __restrict__ ej, const int* __restrict__ ei,
    const float* __restrict__ s_i, const float* __restrict__ s_j,
    float* __restrict__ denom, int* __restrict__ rowoff,
    int2* __restrict__ csr) {
    int t = blockIdx.x * blockDim.x + threadIdx.x;
    if (t >= E_EDGES) return;
    int j = ej[t];
    int i = ei[t];
    float ex = expf(lrelu(s_i[i] + s_j[j]));
    atomicAdd(&denom[j], ex);
    int pos = atomicAdd(&rowoff[i], 1);
    int2 v;
    v.x = j;
    v.y = __float_as_int(ex);
    csr[pos] = v;
}

template <bool BF16>
__global__ __launch_bounds__(256) void k_gather(
    const int* __restrict__ rowend, const int2* __restrict__ csr,
    const float* __restrict__ denom, const float* __restrict__ x,
    const unsigned short* __restrict__ xb, float* __restrict__ out) {
    int wave = (blockIdx.x * blockDim.x + threadIdx.x) >> 6;
    int half = (threadIdx.x >> 5) & 1;
    int l32  = threadIdx.x & 31;
    int node = wave * 2 + half;
    if (node >= N_NODES) return;
    int end = rowend[node];
    int start = (node == 0) ? 0 : rowend[node - 1];
    int len = end - start;
    float ax = 0.f, ay = 0.f, az = 0.f, aw = 0.f;
    for (int off = 0; off < len; off += 32) {
        int m = len - off;
        if (m > 32) m = 32;
        int jv = 0;
        float av = 0.f;
        if (l32 < m) {
            int2 v = csr[start + off + l32];
            jv = v.x;
            av = __int_as_float(v.y) / (denom[jv] + EPS_DEN);
        }
        for (int e = 0; e < m; ++e) {
            int j = __shfl(jv, e, 32);
            float a = __shfl(av, e, 32);
            if (BF16) {
                const uint2* xr = (const uint2*)(xb + (size_t)j * HDIM);
                uint2 v = xr[l32];
                ax += a * __uint_as_float((v.x & 0xFFFFu) << 16);
                ay += a * __uint_as_float(v.x & 0xFFFF0000u);
                az += a * __uint_as_float((v.y & 0xFFFFu) << 16);
                aw += a * __uint_as_float(v.y & 0xFFFF0000u);
            } else {
                const float4* xr = (const float4*)(x + (size_t)j * HDIM);
                float4 v = xr[l32];
                ax += a * v.x;
                ay += a * v.y;
                az += a * v.z;
                aw += a * v.w;
            }
        }
    }
    float4 o;
    o.x = fmaxf(ax, 0.f);
    o.y = fmaxf(ay, 0.f);
    o.z = fmaxf(az, 0.f);
    o.w = fmaxf(aw, 0.f);
    ((float4*)(out + (size_t)node * HDIM))[l32] = o;
}

extern "C" void kernel_launch(void* const* d_in, const int* in_sizes, int n_in,
                              void* d_out, int out_size, void* d_ws, size_t ws_size,
                              hipStream_t stream) {
    const float* x    = (const float*)d_in[0];
    const int*   eidx = (const int*)d_in[1];   // [2, E] int32: row0 = j, row1 = i
    const float* w_i  = (const float*)d_in[3];
    const float* w_j  = (const float*)d_in[4];
    float* out = (float*)d_out;

    const int* ej = eidx;
    const int* ei = eidx + E_EDGES;

    const int EB  = (E_EDGES + 255) / 256;
    const int EB2 = (E_EDGES / 2 + 255) / 256;
    const int EB4 = (E_EDGES / 4 + 255) / 256;
    const int NB  = (N_NODES * 64 + 255) / 256;
    const int NB2 = (((N_NODES + 1) / 2) * 64 + 255) / 256;

    // ---- pad-path layout ----
    // s_i [0,4N) s_j [4N,8N) denom [8N,12N) cursor [12N,16N)
    // csr_pad [16N, 16N+8*N*64)  xb after
    float* s_i    = (float*)d_ws;
    float* s_j    = s_i + N_NODES;
    float* denom  = s_j + N_NODES;
    int*   cursor = (int*)(denom + N_NODES);
    size_t pad_csr_off = (size_t)16 * N_NODES;
    size_t pad_xb_off  = pad_csr_off + (size_t)8 * N_NODES * ROW_CAP;
    size_t need_pad_bf16 = pad_xb_off + (size_t)2 * N_NODES * HDIM;   // ~78.4 MB
    size_t need_pad_f32  = pad_xb_off;                                // ~52.8 MB

    if (ws_size >= need_pad_f32) {
        bool bf16 = (ws_size >= need_pad_bf16);
        int2* csr = (int2*)((char*)d_ws + pad_csr_off);
        unsigned short* xb = (unsigned short*)((char*)d_ws + pad_xb_off);
        if (bf16) {
            k_scores_cast<true><<<NB, 256, 0, stream>>>(x, w_i, w_j, s_i, s_j,
                                                        (unsigned*)xb, denom, cursor);
        } else {
            k_scores_cast<false><<<NB, 256, 0, stream>>>(x, w_i, w_j, s_i, s_j,
                                                         nullptr, denom, cursor);
        }
        k_scatter_pad2<<<EB2, 256, 0, stream>>>((const int2*)ej, (const int2*)ei,
                                                s_i, s_j, denom, cursor, csr);
        if (bf16) {
            k_gather_pad<true><<<NB2, 256, 0, stream>>>(cursor, csr, denom, x, xb, out);
        } else {
            k_gather_pad<false><<<NB2, 256, 0, stream>>>(cursor, csr, denom, x, xb, out);
        }
        return;
    }

    // ---- dense fallback (r8/r9 layout, verified) ----
    int*  rowoff   = cursor;                 // same slot
    int*  blocksum = rowoff + N_NODES;
    int2* csr      = (int2*)(blocksum + SCAN_BLOCKS);
    size_t xb_off  = (size_t)16 * N_NODES + SCAN_BLOCKS * 4 + (size_t)8 * E_EDGES;
    unsigned short* xb = (unsigned short*)((char*)d_ws + xb_off);
    size_t need_bf16 = xb_off + (size_t)2 * N_NODES * HDIM;   // ~40.0 MB
    bool bf16 = (ws_size >= need_bf16);

    if (bf16) {
        k_scores_cast<true><<<NB, 256, 0, stream>>>(x, w_i, w_j, s_i, s_j,
                                                    (unsigned*)xb, denom, rowoff);
    } else {
        k_scores_cast<false><<<NB, 256, 0, stream>>>(x, w_i, w_j, s_i, s_j,
                                                     nullptr, denom, rowoff);
    }
    k_count<<<EB4, 256, 0, stream>>>((const int4*)ei, rowoff);
    k_scanA<<<SCAN_BLOCKS, SCAN_TPB, 0, stream>>>(rowoff, N_NODES, blocksum);
    k_scanB<<<1, SCAN_BLOCKS, 0, stream>>>(blocksum);
    k_scanC<<<SCAN_BLOCKS, SCAN_TPB, 0, stream>>>(rowoff, N_NODES, blocksum);
    k_scatter_denom<<<EB, 256, 0, stream>>>(ej, ei, s_i, s_j, denom, rowoff, csr);
    if (bf16) {
        k_gather<true><<<NB2, 256, 0, stream>>>(rowoff, csr, denom, x, xb, out);
    } else {
        k_gather<false><<<NB2, 256, 0, stream>>>(rowoff, csr, denom, x, xb, out);
    }
}

// Round 11
// 243.519 us; speedup vs baseline: 1.0228x; 1.0228x over previous
//
#include <hip/hip_runtime.h>
#include <math.h>

#define N_NODES 100000
#define E_EDGES 1600000
#define HDIM 128
#define NEG_SLOPE 0.01f
#define EPS_DEN 1e-16f
#define ROW_CAP 64      // in-degree ~ Poisson(16); P(deg>=64) ~ 1e-20

#define SCAN_BLOCKS 256
#define SCAN_TPB 256
#define SCAN_CHUNK ((N_NODES + SCAN_BLOCKS - 1) / SCAN_BLOCKS)   // 391
#define SCAN_STRIP ((SCAN_CHUNK + SCAN_TPB - 1) / SCAN_TPB)      // 2

__device__ __forceinline__ float lrelu(float e) {
    return e > 0.f ? e : NEG_SLOPE * e;
}

// K1: fused per-node scores + optional bf16 cast of x + zero denom/cursor.
// One wave per node; float2 row loads; bf16 row written as packed u32.
template <bool BF16>
__global__ __launch_bounds__(256) void k_scores_cast(
    const float* __restrict__ x, const float* __restrict__ w_i,
    const float* __restrict__ w_j, float* __restrict__ s_i,
    float* __restrict__ s_j, unsigned* __restrict__ xb2,
    float* __restrict__ denom, int* __restrict__ cursor) {
    int wave = (blockIdx.x * blockDim.x + threadIdx.x) >> 6;
    int lane = threadIdx.x & 63;
    if (wave >= N_NODES) return;
    const float2* row = (const float2*)(x + (size_t)wave * HDIM);
    float2 v  = row[lane];
    float2 wi = ((const float2*)w_i)[lane];
    float2 wj = ((const float2*)w_j)[lane];
    if (BF16) {
        unsigned a = __float_as_uint(v.x);
        unsigned b = __float_as_uint(v.y);
        unsigned lo = (a + 0x7FFFu + ((a >> 16) & 1u)) >> 16;
        unsigned hi = (b + 0x7FFFu + ((b >> 16) & 1u)) >> 16;
        xb2[(size_t)wave * (HDIM / 2) + lane] = lo | (hi << 16);
    }
    float vi = v.x * wi.x + v.y * wi.y;
    float vj = v.x * wj.x + v.y * wj.y;
#pragma unroll
    for (int off = 32; off; off >>= 1) {
        vi += __shfl_down(vi, off);
        vj += __shfl_down(vj, off);
    }
    if (lane == 0) {
        s_i[wave] = vi;
        s_j[wave] = vj;
        denom[wave] = 0.f;
        cursor[wave] = 0;
    }
}

// K2 (pad path): fused scatter — r9-validated, 1 edge/thread.
// denom[j] += ex; slot via cursor atomic; store {j, ex} into fixed-cap row.
__global__ __launch_bounds__(256) void k_scatter_pad(
    const int* __restrict__ ej, const int* __restrict__ ei,
    const float* __restrict__ s_i, const float* __restrict__ s_j,
    float* __restrict__ denom, int* __restrict__ cursor,
    int2* __restrict__ csr) {
    int t = blockIdx.x * blockDim.x + threadIdx.x;
    if (t >= E_EDGES) return;
    int j = ej[t];
    int i = ei[t];
    float ex = expf(lrelu(s_i[i] + s_j[j]));
    atomicAdd(&denom[j], ex);
    int slot = atomicAdd(&cursor[i], 1);
    if (slot < ROW_CAP) {
        int2 v;
        v.x = j;
        v.y = __float_as_int(ex);
        csr[(size_t)i * ROW_CAP + slot] = v;
    }
}

// K3 (pad path): gather SPMM + ReLU — r9-validated. Two nodes per wave;
// independent 32-lane halves; width-32 shuffles; uniform trip count;
// alpha = stored_ex/(denom[j]+eps) at stage time.
template <bool BF16>
__global__ __launch_bounds__(256) void k_gather_pad(
    const int* __restrict__ cursor, const int2* __restrict__ csr,
    const float* __restrict__ denom, const float* __restrict__ x,
    const unsigned short* __restrict__ xb, float* __restrict__ out) {
    int wave = (blockIdx.x * blockDim.x + threadIdx.x) >> 6;
    int half = (threadIdx.x >> 5) & 1;
    int l32  = threadIdx.x & 31;
    int node = wave * 2 + half;
    if (node >= N_NODES) return;
    int len = cursor[node];
    if (len > ROW_CAP) len = ROW_CAP;
    int start = node * ROW_CAP;
    float ax = 0.f, ay = 0.f, az = 0.f, aw = 0.f;
    for (int off = 0; off < len; off += 32) {
        int m = len - off;
        if (m > 32) m = 32;
        int jv = 0;
        float av = 0.f;
        if (l32 < m) {
            int2 v = csr[start + off + l32];
            jv = v.x;
            av = __int_as_float(v.y) / (denom[jv] + EPS_DEN);
        }
        for (int e = 0; e < m; ++e) {
            int j = __shfl(jv, e, 32);
            float a = __shfl(av, e, 32);
            if (BF16) {
                const uint2* xr = (const uint2*)(xb + (size_t)j * HDIM);
                uint2 v = xr[l32];
                ax += a * __uint_as_float((v.x & 0xFFFFu) << 16);
                ay += a * __uint_as_float(v.x & 0xFFFF0000u);
                az += a * __uint_as_float((v.y & 0xFFFFu) << 16);
                aw += a * __uint_as_float(v.y & 0xFFFF0000u);
            } else {
                const float4* xr = (const float4*)(x + (size_t)j * HDIM);
                float4 v = xr[l32];
                ax += a * v.x;
                ay += a * v.y;
                az += a * v.z;
                aw += a * v.w;
            }
        }
    }
    float4 o;
    o.x = fmaxf(ax, 0.f);
    o.y = fmaxf(ay, 0.f);
    o.z = fmaxf(az, 0.f);
    o.w = fmaxf(aw, 0.f);
    ((float4*)(out + (size_t)node * HDIM))[l32] = o;
}

// ======== dense fallback (r8/r9-verified) ========
__global__ __launch_bounds__(256) void k_count(
    const int4* __restrict__ ei4, int* __restrict__ counts) {
    int t = blockIdx.x * blockDim.x + threadIdx.x;
    if (t >= E_EDGES / 4) return;
    int4 v = ei4[t];
    atomicAdd(&counts[v.x], 1);
    atomicAdd(&counts[v.y], 1);
    atomicAdd(&counts[v.z], 1);
    atomicAdd(&counts[v.w], 1);
}

__global__ __launch_bounds__(SCAN_TPB) void k_scanA(
    const int* __restrict__ data, int n, int* __restrict__ blocksum) {
    __shared__ int red[SCAN_TPB];
    int b = blockIdx.x, t = threadIdx.x;
    int begin = b * SCAN_CHUNK + t * SCAN_STRIP;
    int lim = (b + 1) * SCAN_CHUNK;
    if (lim > n) lim = n;
    int end = begin + SCAN_STRIP;
    if (end > lim) end = lim;
    int s = 0;
    for (int k = begin; k < end; ++k) s += data[k];
    red[t] = s;
    __syncthreads();
    for (int off = SCAN_TPB / 2; off; off >>= 1) {
        if (t < off) red[t] += red[t + off];
        __syncthreads();
    }
    if (t == 0) blocksum[b] = red[0];
}

__global__ __launch_bounds__(SCAN_BLOCKS) void k_scanB(int* __restrict__ blocksum) {
    __shared__ int s[SCAN_BLOCKS];
    int t = threadIdx.x;
    s[t] = blocksum[t];
    __syncthreads();
    for (int off = 1; off < SCAN_BLOCKS; off <<= 1) {
        int v = (t >= off) ? s[t - off] : 0;
        __syncthreads();
        s[t] += v;
        __syncthreads();
    }
    blocksum[t] = (t == 0) ? 0 : s[t - 1];
}

__global__ __launch_bounds__(SCAN_TPB) void k_scanC(
    int* __restrict__ data, int n, const int* __restrict__ blocksum) {
    __shared__ int s[SCAN_TPB];
    int b = blockIdx.x, t = threadIdx.x;
    int begin = b * SCAN_CHUNK + t * SCAN_STRIP;
    int lim = (b + 1) * SCAN_CHUNK;
    if (lim > n) lim = n;
    int v0 = 0, v1 = 0;            // SCAN_STRIP == 2
    if (begin < lim)      v0 = data[begin];
    if (begin + 1 < lim)  v1 = data[begin + 1];
    s[t] = v0 + v1;
    __syncthreads();
    for (int off = 1; off < SCAN_TPB; off <<= 1) {
        int v = (t >= off) ? s[t - off] : 0;
        __syncthreads();
        s[t] += v;
        __syncthreads();
    }
    int pref = blocksum[b] + ((t == 0) ? 0 : s[t - 1]);
    if (begin < lim)     data[begin] = pref;
    if (begin + 1 < lim) data[begin + 1] = pref + v0;
}

__global__ __launch_bounds__(256) void k_scatter_denom(
    const int* __restrict__ ej, const int* __restrict__ ei,
    const float* __restrict__ s_i, const float* __restrict__ s_j,
    float* __restrict__ denom, int* __restrict__ rowoff,
    int2* __restrict__ csr) {
    int t = blockIdx.x * blockDim.x + threadIdx.x;
    if (t >= E_EDGES) return;
    int j = ej[t];
    int i = ei[t];
    float ex = expf(lrelu(s_i[i] + s_j[j]));
    atomicAdd(&denom[j], ex);
    int pos = atomicAdd(&rowoff[i], 1);
    int2 v;
    v.x = j;
    v.y = __float_as_int(ex);
    csr[pos] = v;
}

template <bool BF16>
__global__ __launch_bounds__(256) void k_gather(
    const int* __restrict__ rowend, const int2* __restrict__ csr,
    const float* __restrict__ denom, const float* __restrict__ x,
    const unsigned short* __restrict__ xb, float* __restrict__ out) {
    int wave = (blockIdx.x * blockDim.x + threadIdx.x) >> 6;
    int half = (threadIdx.x >> 5) & 1;
    int l32  = threadIdx.x & 31;
    int node = wave * 2 + half;
    if (node >= N_NODES) return;
    int end = rowend[node];
    int start = (node == 0) ? 0 : rowend[node - 1];
    int len = end - start;
    float ax = 0.f, ay = 0.f, az = 0.f, aw = 0.f;
    for (int off = 0; off < len; off += 32) {
        int m = len - off;
        if (m > 32) m = 32;
        int jv = 0;
        float av = 0.f;
        if (l32 < m) {
            int2 v = csr[start + off + l32];
            jv = v.x;
            av = __int_as_float(v.y) / (denom[jv] + EPS_DEN);
        }
        for (int e = 0; e < m; ++e) {
            int j = __shfl(jv, e, 32);
            float a = __shfl(av, e, 32);
            if (BF16) {
                const uint2* xr = (const uint2*)(xb + (size_t)j * HDIM);
                uint2 v = xr[l32];
                ax += a * __uint_as_float((v.x & 0xFFFFu) << 16);
                ay += a * __uint_as_float(v.x & 0xFFFF0000u);
                az += a * __uint_as_float((v.y & 0xFFFFu) << 16);
                aw += a * __uint_as_float(v.y & 0xFFFF0000u);
            } else {
                const float4* xr = (const float4*)(x + (size_t)j * HDIM);
                float4 v = xr[l32];
                ax += a * v.x;
                ay += a * v.y;
                az += a * v.z;
                aw += a * v.w;
            }
        }
    }
    float4 o;
    o.x = fmaxf(ax, 0.f);
    o.y = fmaxf(ay, 0.f);
    o.z = fmaxf(az, 0.f);
    o.w = fmaxf(aw, 0.f);
    ((float4*)(out + (size_t)node * HDIM))[l32] = o;
}

extern "C" void kernel_launch(void* const* d_in, const int* in_sizes, int n_in,
                              void* d_out, int out_size, void* d_ws, size_t ws_size,
                              hipStream_t stream) {
    const float* x    = (const float*)d_in[0];
    const int*   eidx = (const int*)d_in[1];   // [2, E] int32: row0 = j, row1 = i
    const float* w_i  = (const float*)d_in[3];
    const float* w_j  = (const float*)d_in[4];
    float* out = (float*)d_out;

    const int* ej = eidx;
    const int* ei = eidx + E_EDGES;

    const int EB  = (E_EDGES + 255) / 256;
    const int EB4 = (E_EDGES / 4 + 255) / 256;
    const int NB  = (N_NODES * 64 + 255) / 256;
    const int NB2 = (((N_NODES + 1) / 2) * 64 + 255) / 256;

    // ---- pad-path layout ----
    // s_i [0,4N) s_j [4N,8N) denom [8N,12N) cursor [12N,16N)
    // csr_pad [16N, 16N+8*N*64)  xb after
    float* s_i    = (float*)d_ws;
    float* s_j    = s_i + N_NODES;
    float* denom  = s_j + N_NODES;
    int*   cursor = (int*)(denom + N_NODES);
    size_t pad_csr_off = (size_t)16 * N_NODES;
    size_t pad_xb_off  = pad_csr_off + (size_t)8 * N_NODES * ROW_CAP;
    size_t need_pad_bf16 = pad_xb_off + (size_t)2 * N_NODES * HDIM;   // ~78.4 MB
    size_t need_pad_f32  = pad_xb_off;                                // ~52.8 MB

    if (ws_size >= need_pad_f32) {
        bool bf16 = (ws_size >= need_pad_bf16);
        int2* csr = (int2*)((char*)d_ws + pad_csr_off);
        unsigned short* xb = (unsigned short*)((char*)d_ws + pad_xb_off);
        if (bf16) {
            k_scores_cast<true><<<NB, 256, 0, stream>>>(x, w_i, w_j, s_i, s_j,
                                                        (unsigned*)xb, denom, cursor);
        } else {
            k_scores_cast<false><<<NB, 256, 0, stream>>>(x, w_i, w_j, s_i, s_j,
                                                         nullptr, denom, cursor);
        }
        k_scatter_pad<<<EB, 256, 0, stream>>>(ej, ei, s_i, s_j, denom, cursor, csr);
        if (bf16) {
            k_gather_pad<true><<<NB2, 256, 0, stream>>>(cursor, csr, denom, x, xb, out);
        } else {
            k_gather_pad<false><<<NB2, 256, 0, stream>>>(cursor, csr, denom, x, xb, out);
        }
        return;
    }

    // ---- dense fallback (r8/r9 layout, verified) ----
    int*  rowoff   = cursor;                 // same slot
    int*  blocksum = rowoff + N_NODES;
    int2* csr      = (int2*)(blocksum + SCAN_BLOCKS);
    size_t xb_off  = (size_t)16 * N_NODES + SCAN_BLOCKS * 4 + (size_t)8 * E_EDGES;
    unsigned short* xb = (unsigned short*)((char*)d_ws + xb_off);
    size_t need_bf16 = xb_off + (size_t)2 * N_NODES * HDIM;   // ~40.0 MB
    bool bf16 = (ws_size >= need_bf16);

    if (bf16) {
        k_scores_cast<true><<<NB, 256, 0, stream>>>(x, w_i, w_j, s_i, s_j,
                                                    (unsigned*)xb, denom, rowoff);
    } else {
        k_scores_cast<false><<<NB, 256, 0, stream>>>(x, w_i, w_j, s_i, s_j,
                                                     nullptr, denom, rowoff);
    }
    k_count<<<EB4, 256, 0, stream>>>((const int4*)ei, rowoff);
    k_scanA<<<SCAN_BLOCKS, SCAN_TPB, 0, stream>>>(rowoff, N_NODES, blocksum);
    k_scanB<<<1, SCAN_BLOCKS, 0, stream>>>(blocksum);
    k_scanC<<<SCAN_BLOCKS, SCAN_TPB, 0, stream>>>(rowoff, N_NODES, blocksum);
    k_scatter_denom<<<EB, 256, 0, stream>>>(ej, ei, s_i, s_j, denom, rowoff, csr);
    if (bf16) {
        k_gather<true><<<NB2, 256, 0, stream>>>(rowoff, csr, denom, x, xb, out);
    } else {
        k_gather<false><<<NB2, 256, 0, stream>>>(rowoff, csr, denom, x, xb, out);
    }
}